// Round 6
// baseline (177.041 us; speedup 1.0000x reference)
//
#include <hip/hip_runtime.h>
#include <hip/hip_bf16.h>

#define B_   4096
#define S_   32
#define IN_  256
#define H_   128
#define OUT_ 256

typedef __attribute__((ext_vector_type(8))) short bf16x8;
typedef __attribute__((ext_vector_type(4))) float f32x4;
typedef unsigned long long ull;

__device__ __forceinline__ unsigned short f2bf(float f) {
    union { float f; unsigned u; } v; v.f = f;
    unsigned r = v.u + 0x7FFFu + ((v.u >> 16) & 1u);   // round-to-nearest-even
    return (unsigned short)(r >> 16);
}

__device__ __forceinline__ unsigned cvt_pk(float lo, float hi) {
    unsigned r;
    asm("v_cvt_pk_bf16_f32 %0, %1, %2" : "=v"(r) : "v"(lo), "v"(hi));
    return r;
}

__device__ __forceinline__ bf16x8 pack8_pk(float4 a, float4 b) {
    union { unsigned u[4]; bf16x8 v; } r;
    r.u[0] = cvt_pk(a.x, a.y);
    r.u[1] = cvt_pk(a.z, a.w);
    r.u[2] = cvt_pk(b.x, b.y);
    r.u[3] = cvt_pk(b.z, b.w);
    return r.v;
}

// Transpose + f32->bf16 convert for BOTH weight tensors in one launch.
// blocks [0,1024): W1 [S][256][128] -> w1t [S][128][256]
// blocks [1024,2048): W2 [S][128][256] -> w2t [S][256][128]
__global__ void transpose_cvt_both(const float* __restrict__ W1,
                                   const float* __restrict__ W2,
                                   unsigned short* __restrict__ w1t,
                                   unsigned short* __restrict__ w2t) {
    __shared__ float tile[32][33];
    int bid = blockIdx.x;
    const float* in; unsigned short* out; int R, C, rel;
    if (bid < 1024) { in = W1; out = w1t; R = IN_; C = H_;  rel = bid; }
    else            { in = W2; out = w2t; R = H_; C = OUT_; rel = bid - 1024; }
    const int tilesR = R >> 5, tilesC = C >> 5;
    const int s   = rel / (tilesR * tilesC);
    const int rem = rel % (tilesR * tilesC);
    const int tr  = rem / tilesC, tc = rem % tilesC;
    const float* ip = in + (size_t)s * R * C;
    unsigned short* op = out + (size_t)s * C * R;
    const int t  = threadIdx.x;
    const int c  = t & 31;
    const int r4 = t >> 5;
#pragma unroll
    for (int i = 0; i < 4; ++i) {
        int r = r4 * 4 + i;
        tile[r][c] = ip[(size_t)(tr * 32 + r) * C + tc * 32 + c];
    }
    __syncthreads();
#pragma unroll
    for (int i = 0; i < 4; ++i) {
        int orow = r4 * 4 + i;
        int ocol = c;
        op[(size_t)(tc * 32 + orow) * R + tr * 32 + ocol] = f2bf(tile[ocol][orow]);
    }
}

// Wave-autonomous fused MLP: each wave owns one (subband, 16-row) tile.
// NO barriers. grid = 2048 blocks x 256 thr (4 waves) = 8192 waves = 8192 tiles.
// Layer 1 computed SWAPPED: mfma(A=W1 rows (h,k), B=x rows (m,k)) -> D[h][m],
// so x loads go global->reg directly in B-fragment layout. Repack h<->lane
// through a per-wave 4KB swizzled LDS slice; layer 2 standard orientation.
__global__ __launch_bounds__(256, 6) void subband_fused_kernel(
        const float* __restrict__ x,
        const unsigned short* __restrict__ w1t,   // [S][H][IN] bf16
        const float* __restrict__ b1,             // [S][H]
        const unsigned short* __restrict__ w2t,   // [S][OUT][H] bf16
        const float* __restrict__ b2,             // [S][OUT]
        float* __restrict__ out) {
    __shared__ __align__(16) unsigned char lds[16384];   // 4 waves x 4KB, no sharing

    // XCD swizzle (bijective, 2048 % 8 == 0): XCD c serves subbands [4c, 4c+4)
    // -> 512 KB of bf16 weights per XCD L2.
    const int raw = blockIdx.x;
    const int bid = (raw & 7) * 256 + (raw >> 3);
    const int s   = bid >> 6;                 // 64 blocks per subband
    const int tid = threadIdx.x;
    const int w   = tid >> 6;
    const int lane = tid & 63;
    const int l15 = lane & 15;
    const int l4  = lane >> 4;
    const int tt  = (bid & 63) * 4 + w;       // tile 0..255 within subband
    const int r0  = tt * 16;

    unsigned char* hs = lds + w * 4096;       // per-wave [16 rows][256 B], XOR-swizzled

    // ---- X tile (16 rows) -> registers as layer-1 B-fragments (bf16) ----
    // frag kk: lane holds x[r0 + l15][kk*32 + l4*8 .. +8)
    bf16x8 xb[8];
    {
        const float* xr = x + ((size_t)(r0 + l15) * S_ + s) * IN_ + l4 * 8;
#pragma unroll
        for (int kk = 0; kk < 8; ++kk) {
            float4 lo = *(const float4*)(xr + kk * 32);
            float4 hi = *(const float4*)(xr + kk * 32 + 4);
            xb[kk] = pack8_pk(lo, hi);
        }
    }

    // ---- layer 1 (swapped): D[h][m] = W1[h,:] . x[m,:], quartered over h ----
    const unsigned short* w1s = w1t + (size_t)s * H_ * IN_;
#pragma unroll
    for (int hq = 0; hq < 4; ++hq) {
        f32x4 acc[2];
#pragma unroll
        for (int hf = 0; hf < 2; ++hf) {
            // bias for rows h = hq*32 + hf*16 + l4*4 + i  (vector float4 load)
            const float4 bv = *(const float4*)(b1 + s * H_ + hq * 32 + hf * 16 + l4 * 4);
            acc[hf][0] = bv.x; acc[hf][1] = bv.y; acc[hf][2] = bv.z; acc[hf][3] = bv.w;
        }
        __builtin_amdgcn_s_setprio(1);
#pragma unroll
        for (int kk = 0; kk < 8; ++kk) {
            bf16x8 wf[2];
#pragma unroll
            for (int hf = 0; hf < 2; ++hf)
                wf[hf] = *(const bf16x8*)(w1s
                    + (size_t)(hq * 32 + hf * 16 + l15) * IN_ + kk * 32 + l4 * 8);
#pragma unroll
            for (int hf = 0; hf < 2; ++hf)
                acc[hf] = __builtin_amdgcn_mfma_f32_16x16x32_bf16(
                    wf[hf], xb[kk], acc[hf], 0, 0, 0);
        }
        __builtin_amdgcn_s_setprio(0);
        // relu + cvt_pk; 4 h-consecutive bf16 -> one b64 write.
        // hs layout: byte = m*256 + ((h*2) ^ ((m&7)<<4)), m = l15
#pragma unroll
        for (int hf = 0; hf < 2; ++hf) {
            const int m  = l15;
            const int h0 = hq * 32 + hf * 16 + l4 * 4;
            unsigned plo = cvt_pk(fmaxf(acc[hf][0], 0.f), fmaxf(acc[hf][1], 0.f));
            unsigned phi = cvt_pk(fmaxf(acc[hf][2], 0.f), fmaxf(acc[hf][3], 0.f));
            ull p = (ull)plo | ((ull)phi << 32);
            *(ull*)(hs + m * 256 + ((h0 * 2) ^ ((m & 7) << 4))) = p;
        }
    }
    // same-wave LDS RAW: drain DS queue, and fence the compiler (rule #18).
    __asm__ __volatile__("s_waitcnt lgkmcnt(0)" ::: "memory");
    __builtin_amdgcn_sched_barrier(0);

    // ---- layer 2 (standard): A from hs (lane l15 = m, 8 contiguous h) ----
    bf16x8 a2[4];
    {
        const int m = l15;
#pragma unroll
        for (int kk = 0; kk < 4; ++kk)
            a2[kk] = *(const bf16x8*)(hs + m * 256
                + ((kk * 64 + l4 * 16) ^ ((m & 7) << 4)));
    }
    const unsigned short* w2s = w2t + (size_t)s * OUT_ * H_;
#pragma unroll
    for (int oq = 0; oq < 4; ++oq) {
        float b2v[4];
#pragma unroll
        for (int of = 0; of < 4; ++of)
            b2v[of] = b2[s * OUT_ + oq * 64 + of * 16 + l15];
        f32x4 acc[4];
#pragma unroll
        for (int of = 0; of < 4; ++of)
#pragma unroll
            for (int i = 0; i < 4; ++i)
                acc[of][i] = b2v[of];
        __builtin_amdgcn_s_setprio(1);
#pragma unroll
        for (int kk = 0; kk < 4; ++kk) {
            bf16x8 wf[4];
#pragma unroll
            for (int of = 0; of < 4; ++of)
                wf[of] = *(const bf16x8*)(w2s
                    + (size_t)(oq * 64 + of * 16 + l15) * H_ + kk * 32 + l4 * 8);
#pragma unroll
            for (int of = 0; of < 4; ++of)
                acc[of] = __builtin_amdgcn_mfma_f32_16x16x32_bf16(
                    a2[kk], wf[of], acc[of], 0, 0, 0);
        }
        __builtin_amdgcn_s_setprio(0);
        // stores: 16 lanes x 4B contiguous (64B) x 4 rows per instruction
#pragma unroll
        for (int of = 0; of < 4; ++of)
#pragma unroll
            for (int i = 0; i < 4; ++i) {
                const int r = r0 + l4 * 4 + i;
                out[((size_t)r * S_ + s) * OUT_ + oq * 64 + of * 16 + l15]
                    = acc[of][i];
            }
    }
}

extern "C" void kernel_launch(void* const* d_in, const int* in_sizes, int n_in,
                              void* d_out, int out_size, void* d_ws, size_t ws_size,
                              hipStream_t stream) {
    const float* x  = (const float*)d_in[0];
    const float* W1 = (const float*)d_in[1];
    const float* b1 = (const float*)d_in[2];
    const float* W2 = (const float*)d_in[3];
    const float* b2 = (const float*)d_in[4];
    float* out = (float*)d_out;

    unsigned short* w1t = (unsigned short*)d_ws;                 // [S][H][IN]  bf16: 2 MiB
    unsigned short* w2t = w1t + (size_t)S_ * H_ * IN_;           // [S][OUT][H] bf16: 2 MiB

    transpose_cvt_both<<<2048, 256, 0, stream>>>(W1, W2, w1t, w2t);
    subband_fused_kernel<<<2048, 256, 0, stream>>>(x, w1t, b1, w2t, b2, out);
}

// Round 7
// 164.721 us; speedup vs baseline: 1.0748x; 1.0748x over previous
//
#include <hip/hip_runtime.h>
#include <hip/hip_bf16.h>

#define B_   4096
#define S_   32
#define IN_  256
#define H_   128
#define OUT_ 256
#define BM_  32    // rows per tile
#define T_   4     // tiles per block -> 128 rows per block

typedef __attribute__((ext_vector_type(8))) short bf16x8;
typedef __attribute__((ext_vector_type(4))) float f32x4;
typedef unsigned long long ull;

__device__ __forceinline__ unsigned short f2bf(float f) {
    union { float f; unsigned u; } v; v.f = f;
    unsigned r = v.u + 0x7FFFu + ((v.u >> 16) & 1u);   // round-to-nearest-even
    return (unsigned short)(r >> 16);
}

__device__ __forceinline__ unsigned cvt_pk(float lo, float hi) {
    unsigned r;
    asm("v_cvt_pk_bf16_f32 %0, %1, %2" : "=v"(r) : "v"(lo), "v"(hi));
    return r;
}

// Transpose + f32->bf16 convert for BOTH weight tensors in one launch.
// blocks [0,1024): W1 [S][256][128] -> w1t [S][128][256]
// blocks [1024,2048): W2 [S][128][256] -> w2t [S][256][128]
__global__ void transpose_cvt_both(const float* __restrict__ W1,
                                   const float* __restrict__ W2,
                                   unsigned short* __restrict__ w1t,
                                   unsigned short* __restrict__ w2t) {
    __shared__ float tile[32][33];
    int bid = blockIdx.x;
    const float* in; unsigned short* out; int R, C, rel;
    if (bid < 1024) { in = W1; out = w1t; R = IN_; C = H_;  rel = bid; }
    else            { in = W2; out = w2t; R = H_; C = OUT_; rel = bid - 1024; }
    const int tilesR = R >> 5, tilesC = C >> 5;
    const int s   = rel / (tilesR * tilesC);
    const int rem = rel % (tilesR * tilesC);
    const int tr  = rem / tilesC, tc = rem % tilesC;
    const float* ip = in + (size_t)s * R * C;
    unsigned short* op = out + (size_t)s * C * R;
    const int t  = threadIdx.x;
    const int c  = t & 31;
    const int r4 = t >> 5;
#pragma unroll
    for (int i = 0; i < 4; ++i) {
        int r = r4 * 4 + i;
        tile[r][c] = ip[(size_t)(tr * 32 + r) * C + tc * 32 + c];
    }
    __syncthreads();
#pragma unroll
    for (int i = 0; i < 4; ++i) {
        int orow = r4 * 4 + i;
        int ocol = c;
        op[(size_t)(tc * 32 + orow) * R + tr * 32 + ocol] = f2bf(tile[ocol][orow]);
    }
}

// Fused per-subband MLP: block-cooperative, T14-pipelined, single xs buffer.
// grid = 1024 blocks (4/CU), block = 256 threads (4 waves).
// Each block: one subband, 4 tiles of 32 rows. Weights streamed from L2.
__global__ __launch_bounds__(256, 4) void subband_fused_kernel(
        const float* __restrict__ x,
        const unsigned short* __restrict__ w1t,   // [S][H][IN] bf16
        const float* __restrict__ b1,             // [S][H]
        const unsigned short* __restrict__ w2t,   // [S][OUT][H] bf16
        const float* __restrict__ b2,             // [S][OUT]
        float* __restrict__ out) {
    // LDS: [0,16384) xs = [32 rows][512 B] bf16 swizzled; [16384,24576) hs.
    __shared__ __align__(16) unsigned char lds[24576];
    unsigned char* xs = lds;
    unsigned char* hs = lds + 16384;

    // Bijective XCD swizzle (1024 % 8 == 0): XCD c -> bids [128c,128c+128)
    // -> subbands [4c,4c+4) -> 512 KB bf16 weights per XCD L2.
    const int raw = blockIdx.x;
    const int bid = (raw & 7) * 128 + (raw >> 3);
    const int s   = bid >> 5;                 // 32 blocks per subband
    const int rowbase = (bid & 31) * (BM_ * T_);

    const int tid  = threadIdx.x;
    const int lane = tid & 63;
    const int w    = tid >> 6;           // wave 0..3
    const int l15  = lane & 15;
    const int l4   = lane >> 4;          // 0..3

    const int c4 = tid & 63;             // float4 column index 0..63 (staging)
    const int rb = tid >> 6;             // staging row offset 0..3

    const unsigned short* w1s = w1t + (size_t)s * H_ * IN_;
    const unsigned short* w2s = w2t + (size_t)s * OUT_ * H_;

    float bias1[2];
#pragma unroll
    for (int ct = 0; ct < 2; ++ct) bias1[ct] = b1[s * H_ + (w << 5) + ct * 16 + l15];

    // ---------- prologue: issue x-loads for tile 0 ----------
    float4 v[8];
#define ISSUE_LOADS(T)                                                                 \
    {                                                                                  \
        const int r0_ = rowbase + (T) * BM_;                                           \
        _Pragma("unroll")                                                              \
        for (int it = 0; it < 8; ++it)                                                 \
            v[it] = *(const float4*)(x + ((size_t)(r0_ + it * 4 + rb) * S_ + s) * IN_  \
                                       + (c4 << 2));                                   \
    }
    ISSUE_LOADS(0);

#pragma unroll 1
    for (int t = 0; t < T_; ++t) {
        // ---- step 1: convert v -> xs (bf16, swizzled) ----
        // WAR vs prev iter's layer-1 xs reads: covered by barrier B below.
#pragma unroll
        for (int it = 0; it < 8; ++it) {
            const int r = it * 4 + rb;
            ull p = (ull)cvt_pk(v[it].x, v[it].y) | ((ull)cvt_pk(v[it].z, v[it].w) << 32);
            *(ull*)(xs + r * 512 + ((c4 << 3) ^ ((r & 7) << 4))) = p;
        }
        __syncthreads();                       // barrier A: xs ready, prev hs reads done

        if (t + 1 < T_) ISSUE_LOADS(t + 1);    // prefetch next tile under both layers

        // ---- layer 1: H[32][128] = relu(X @ W1 + b1), wave w owns cols [32w,32w+32) ----
        f32x4 acc1[2][2];
#pragma unroll
        for (int rt = 0; rt < 2; ++rt)
#pragma unroll
            for (int ct = 0; ct < 2; ++ct)
#pragma unroll
                for (int i = 0; i < 4; ++i) acc1[rt][ct][i] = bias1[ct];
        __builtin_amdgcn_s_setprio(1);
#pragma unroll
        for (int kk = 0; kk < 8; ++kk) {
            const int kb = kk * 32 + l4 * 8;
            bf16x8 a[2];
#pragma unroll
            for (int rt = 0; rt < 2; ++rt) {
                const int r = rt * 16 + l15;
                a[rt] = *(const bf16x8*)(xs + r * 512 + ((kb * 2) ^ ((r & 7) << 4)));
            }
            bf16x8 bb[2];
#pragma unroll
            for (int ct = 0; ct < 2; ++ct)
                bb[ct] = *(const bf16x8*)(w1s
                    + (size_t)((w << 5) + ct * 16 + l15) * IN_ + kb);
#pragma unroll
            for (int rt = 0; rt < 2; ++rt)
#pragma unroll
                for (int ct = 0; ct < 2; ++ct)
                    acc1[rt][ct] = __builtin_amdgcn_mfma_f32_16x16x32_bf16(
                        a[rt], bb[ct], acc1[rt][ct], 0, 0, 0);
        }
        __builtin_amdgcn_s_setprio(0);
        // relu -> hs (bf16, swizzled). C/D: col = l15 (n), row = l4*4+i (m).
        // WAR vs prev iter's layer-2 hs reads: covered by barrier A above.
#pragma unroll
        for (int rt = 0; rt < 2; ++rt)
#pragma unroll
            for (int ct = 0; ct < 2; ++ct)
#pragma unroll
                for (int i = 0; i < 4; ++i) {
                    float hv = fmaxf(acc1[rt][ct][i], 0.0f);
                    const int r = rt * 16 + l4 * 4 + i;
                    const int n = (w << 5) + ct * 16 + l15;
                    *(unsigned short*)(hs + r * 256 + ((n * 2) ^ ((r & 7) << 4))) = f2bf(hv);
                }
        __syncthreads();                       // barrier B: hs ready, layer-1 xs reads done

        // ---- layer 2: OUT[32][256] = H @ W2 + b2, wave w owns cols [64w,64w+64) ----
        const int r0t = rowbase + t * BM_;
#pragma unroll
        for (int oq = 0; oq < 2; ++oq) {
            float bias2[2];
#pragma unroll
            for (int ct = 0; ct < 2; ++ct)
                bias2[ct] = b2[s * OUT_ + (w << 6) + oq * 32 + ct * 16 + l15];
            f32x4 acc2[2][2];
#pragma unroll
            for (int rt = 0; rt < 2; ++rt)
#pragma unroll
                for (int ct = 0; ct < 2; ++ct)
#pragma unroll
                    for (int i = 0; i < 4; ++i) acc2[rt][ct][i] = bias2[ct];
            __builtin_amdgcn_s_setprio(1);
#pragma unroll
            for (int kk = 0; kk < 4; ++kk) {
                const int kb = kk * 32 + l4 * 8;
                bf16x8 a[2];
#pragma unroll
                for (int rt = 0; rt < 2; ++rt) {
                    const int r = rt * 16 + l15;
                    a[rt] = *(const bf16x8*)(hs + r * 256 + ((kb * 2) ^ ((r & 7) << 4)));
                }
                bf16x8 bb[2];
#pragma unroll
                for (int ct = 0; ct < 2; ++ct)
                    bb[ct] = *(const bf16x8*)(w2s
                        + (size_t)((w << 6) + oq * 32 + ct * 16 + l15) * H_ + kb);
#pragma unroll
                for (int rt = 0; rt < 2; ++rt)
#pragma unroll
                    for (int ct = 0; ct < 2; ++ct)
                        acc2[rt][ct] = __builtin_amdgcn_mfma_f32_16x16x32_bf16(
                            a[rt], bb[ct], acc2[rt][ct], 0, 0, 0);
            }
            __builtin_amdgcn_s_setprio(0);
            // stores: 16 lanes x 4B contiguous (64B) per (rt,ct,i)
#pragma unroll
            for (int rt = 0; rt < 2; ++rt)
#pragma unroll
                for (int ct = 0; ct < 2; ++ct)
#pragma unroll
                    for (int i = 0; i < 4; ++i) {
                        const int r = r0t + rt * 16 + l4 * 4 + i;
                        const int n = (w << 6) + oq * 32 + ct * 16 + l15;
                        out[((size_t)r * S_ + s) * OUT_ + n] = acc2[rt][ct][i];
                    }
        }
    }
#undef ISSUE_LOADS
}

extern "C" void kernel_launch(void* const* d_in, const int* in_sizes, int n_in,
                              void* d_out, int out_size, void* d_ws, size_t ws_size,
                              hipStream_t stream) {
    const float* x  = (const float*)d_in[0];
    const float* W1 = (const float*)d_in[1];
    const float* b1 = (const float*)d_in[2];
    const float* W2 = (const float*)d_in[3];
    const float* b2 = (const float*)d_in[4];
    float* out = (float*)d_out;

    unsigned short* w1t = (unsigned short*)d_ws;                 // [S][H][IN]  bf16: 2 MiB
    unsigned short* w2t = w1t + (size_t)S_ * H_ * IN_;           // [S][OUT][H] bf16: 2 MiB

    transpose_cvt_both<<<2048, 256, 0, stream>>>(W1, W2, w1t, w2t);
    subband_fused_kernel<<<1024, 256, 0, stream>>>(x, w1t, b1, w2t, b2, out);
}

// Round 8
// 84.050 us; speedup vs baseline: 2.1064x; 1.9598x over previous
//
#include <hip/hip_runtime.h>
#include <hip/hip_bf16.h>

#define B_   4096
#define S_   32
#define IN_  256
#define H_   128
#define OUT_ 256
#define BM_  64    // rows per block (one tile per block, R1 tiling)

typedef __attribute__((ext_vector_type(8))) short bf16x8;
typedef __attribute__((ext_vector_type(4))) float f32x4;
typedef unsigned long long ull;

__device__ __forceinline__ unsigned short f2bf(float f) {
    union { float f; unsigned u; } v; v.f = f;
    unsigned r = v.u + 0x7FFFu + ((v.u >> 16) & 1u);   // round-to-nearest-even
    return (unsigned short)(r >> 16);
}

__device__ __forceinline__ unsigned cvt_pk(float lo, float hi) {
    unsigned r;
    asm("v_cvt_pk_bf16_f32 %0, %1, %2" : "=v"(r) : "v"(lo), "v"(hi));
    return r;
}

// Transpose + f32->bf16 convert for BOTH weight tensors in one launch.
// blocks [0,1024): W1 [S][256][128] -> w1t [S][128][256]
// blocks [1024,2048): W2 [S][128][256] -> w2t [S][256][128]
__global__ void transpose_cvt_both(const float* __restrict__ W1,
                                   const float* __restrict__ W2,
                                   unsigned short* __restrict__ w1t,
                                   unsigned short* __restrict__ w2t) {
    __shared__ float tile[32][33];
    int bid = blockIdx.x;
    const float* in; unsigned short* out; int R, C, rel;
    if (bid < 1024) { in = W1; out = w1t; R = IN_; C = H_;  rel = bid; }
    else            { in = W2; out = w2t; R = H_; C = OUT_; rel = bid - 1024; }
    const int tilesR = R >> 5, tilesC = C >> 5;
    const int s   = rel / (tilesR * tilesC);
    const int rem = rel % (tilesR * tilesC);
    const int tr  = rem / tilesC, tc = rem % tilesC;
    const float* ip = in + (size_t)s * R * C;
    unsigned short* op = out + (size_t)s * C * R;
    const int t  = threadIdx.x;
    const int c  = t & 31;
    const int r4 = t >> 5;
#pragma unroll
    for (int i = 0; i < 4; ++i) {
        int r = r4 * 4 + i;
        tile[r][c] = ip[(size_t)(tr * 32 + r) * C + tc * 32 + c];
    }
    __syncthreads();
#pragma unroll
    for (int i = 0; i < 4; ++i) {
        int orow = r4 * 4 + i;
        int ocol = c;
        op[(size_t)(tc * 32 + orow) * R + tr * 32 + ocol] = f2bf(tile[ocol][orow]);
    }
}

// Fused per-subband MLP. R1 tiling (BM=64, one tile/block, grid 2048, 4 waves)
// + register-prestreamed weights: all of a phase's weight fragments are issued
// as a batch ahead of their consuming MFMA loop, so L2 latency is paid once
// per phase (hidden under staging/barrier/previous compute), not per kk.
__global__ __launch_bounds__(256, 3) void subband_fused_kernel(
        const float* __restrict__ x,
        const unsigned short* __restrict__ w1t,   // [S][H][IN] bf16
        const float* __restrict__ b1,             // [S][H]
        const unsigned short* __restrict__ w2t,   // [S][OUT][H] bf16
        const float* __restrict__ b2,             // [S][OUT]
        float* __restrict__ out) {
    // LDS: [0,32768) xs = [64 rows][512 B] bf16 swizzled; [32768,49152) hs = [64][256 B].
    __shared__ __align__(16) unsigned char lds[49152];
    unsigned char* xs = lds;
    unsigned char* hs = lds + 32768;

    // Bijective XCD swizzle (2048 % 8 == 0): XCD c gets bids [256c,256c+256)
    // = subbands [4c,4c+4) -> 512 KB bf16 weights per XCD L2.
    const int raw = blockIdx.x;
    const int bid = (raw & 7) * 256 + (raw >> 3);
    const int s   = bid >> 6;            // 64 blocks per subband
    const int b0  = (bid & 63) << 6;     // first row of this 64-row tile

    const int tid  = threadIdx.x;
    const int lane = tid & 63;
    const int w    = tid >> 6;           // wave 0..3
    const int l15  = lane & 15;
    const int l4   = lane >> 4;          // 0..3

    const int c4 = tid & 63;             // float4 column index (staging)
    const int rb = tid >> 6;             // staging row offset 0..3

    const unsigned short* w1s = w1t + (size_t)s * H_ * IN_;
    const unsigned short* w2s = w2t + (size_t)s * OUT_ * H_;

    // ---- issue ALL x staging loads (16 float4/thread, in flight together) ----
    float4 v[16];
#pragma unroll
    for (int it = 0; it < 16; ++it) {
        const int r = it * 4 + rb;
        v[it] = *(const float4*)(x + ((size_t)(b0 + r) * S_ + s) * IN_ + (c4 << 2));
    }

    // ---- prestream ALL layer-1 weight fragments (latency hides under staging) ----
    // wave w owns H-cols [32w, 32w+32): frag (kk,ct) = rows(h) ct*16+l15, k kk*32+l4*8
    bf16x8 bb1[8][2];
#pragma unroll
    for (int kk = 0; kk < 8; ++kk)
#pragma unroll
        for (int ct = 0; ct < 2; ++ct)
            bb1[kk][ct] = *(const bf16x8*)(w1s
                + (size_t)((w << 5) + ct * 16 + l15) * IN_ + kk * 32 + l4 * 8);

    float bias1[2];
    bias1[0] = b1[s * H_ + (w << 5) + l15];
    bias1[1] = b1[s * H_ + (w << 5) + 16 + l15];
    float bias2[4];
#pragma unroll
    for (int ct = 0; ct < 4; ++ct)
        bias2[ct] = b2[s * OUT_ + (w << 6) + ct * 16 + l15];

    // ---- convert staged x -> xs (bf16, XOR-swizzled) ----
#pragma unroll
    for (int it = 0; it < 16; ++it) {
        const int r = it * 4 + rb;
        ull p = (ull)cvt_pk(v[it].x, v[it].y) | ((ull)cvt_pk(v[it].z, v[it].w) << 32);
        *(ull*)(xs + r * 512 + ((c4 << 3) ^ ((r & 7) << 4))) = p;
    }
    __syncthreads();                       // barrier A: xs ready

    // ---- layer 1: H[64][128] = relu(X @ W1 + b1), wave w cols [32w,32w+32) ----
    f32x4 acc1[4][2];
#pragma unroll
    for (int rt = 0; rt < 4; ++rt)
#pragma unroll
        for (int ct = 0; ct < 2; ++ct)
#pragma unroll
            for (int i = 0; i < 4; ++i) acc1[rt][ct][i] = bias1[ct];
#pragma unroll
    for (int kk = 0; kk < 8; ++kk) {
        const int kb = kk * 32 + l4 * 8;
        bf16x8 a[4];
#pragma unroll
        for (int rt = 0; rt < 4; ++rt) {
            const int r = rt * 16 + l15;
            a[rt] = *(const bf16x8*)(xs + r * 512 + ((kb * 2) ^ ((r & 7) << 4)));
        }
#pragma unroll
        for (int rt = 0; rt < 4; ++rt)
#pragma unroll
            for (int ct = 0; ct < 2; ++ct)
                acc1[rt][ct] = __builtin_amdgcn_mfma_f32_16x16x32_bf16(
                    a[rt], bb1[kk][ct], acc1[rt][ct], 0, 0, 0);
    }

    // ---- prestream layer-2 weights, first half (oq=0: cols [64w,64w+32)) ----
    // latency hides under hs writes + barrier B
    bf16x8 bb2a[4][2];
#pragma unroll
    for (int kk = 0; kk < 4; ++kk)
#pragma unroll
        for (int ct = 0; ct < 2; ++ct)
            bb2a[kk][ct] = *(const bf16x8*)(w2s
                + (size_t)((w << 6) + ct * 16 + l15) * H_ + kk * 32 + l4 * 8);

    // ---- relu -> hs (bf16, swizzled). C/D: col = l15 (n), row = l4*4+i (m) ----
#pragma unroll
    for (int rt = 0; rt < 4; ++rt)
#pragma unroll
        for (int ct = 0; ct < 2; ++ct)
#pragma unroll
            for (int i = 0; i < 4; ++i) {
                float hv = fmaxf(acc1[rt][ct][i], 0.0f);
                const int r = rt * 16 + l4 * 4 + i;
                const int n = (w << 5) + ct * 16 + l15;
                *(unsigned short*)(hs + r * 256 + ((n * 2) ^ ((r & 7) << 4))) = f2bf(hv);
            }
    __syncthreads();                       // barrier B: hs ready

    // ---- prestream layer-2 weights, second half (oq=1), hides under oq0 MFMA ----
    bf16x8 bb2b[4][2];
#pragma unroll
    for (int kk = 0; kk < 4; ++kk)
#pragma unroll
        for (int ct = 0; ct < 2; ++ct)
            bb2b[kk][ct] = *(const bf16x8*)(w2s
                + (size_t)((w << 6) + 32 + ct * 16 + l15) * H_ + kk * 32 + l4 * 8);

    // ---- layer 2, oq = 0: cols [64w, 64w+32) ----
    {
        f32x4 acc2[4][2];
#pragma unroll
        for (int rt = 0; rt < 4; ++rt)
#pragma unroll
            for (int ct = 0; ct < 2; ++ct)
#pragma unroll
                for (int i = 0; i < 4; ++i) acc2[rt][ct][i] = bias2[ct];
#pragma unroll
        for (int kk = 0; kk < 4; ++kk) {
            const int kb = kk * 32 + l4 * 8;
            bf16x8 a[4];
#pragma unroll
            for (int rt = 0; rt < 4; ++rt) {
                const int r = rt * 16 + l15;
                a[rt] = *(const bf16x8*)(hs + r * 256 + ((kb * 2) ^ ((r & 7) << 4)));
            }
#pragma unroll
            for (int rt = 0; rt < 4; ++rt)
#pragma unroll
                for (int ct = 0; ct < 2; ++ct)
                    acc2[rt][ct] = __builtin_amdgcn_mfma_f32_16x16x32_bf16(
                        a[rt], bb2a[kk][ct], acc2[rt][ct], 0, 0, 0);
        }
#pragma unroll
        for (int rt = 0; rt < 4; ++rt)
#pragma unroll
            for (int ct = 0; ct < 2; ++ct)
#pragma unroll
                for (int i = 0; i < 4; ++i) {
                    const int r = b0 + rt * 16 + l4 * 4 + i;
                    const int n = (w << 6) + ct * 16 + l15;
                    out[((size_t)r * S_ + s) * OUT_ + n] = acc2[rt][ct][i];
                }
    }
    // ---- layer 2, oq = 1: cols [64w+32, 64w+64) ----
    {
        f32x4 acc2[4][2];
#pragma unroll
        for (int rt = 0; rt < 4; ++rt)
#pragma unroll
            for (int ct = 0; ct < 2; ++ct)
#pragma unroll
                for (int i = 0; i < 4; ++i) acc2[rt][ct][i] = bias2[2 + ct];
#pragma unroll
        for (int kk = 0; kk < 4; ++kk) {
            const int kb = kk * 32 + l4 * 8;
            bf16x8 a[4];
#pragma unroll
            for (int rt = 0; rt < 4; ++rt) {
                const int r = rt * 16 + l15;
                a[rt] = *(const bf16x8*)(hs + r * 256 + ((kb * 2) ^ ((r & 7) << 4)));
            }
#pragma unroll
            for (int rt = 0; rt < 4; ++rt)
#pragma unroll
                for (int ct = 0; ct < 2; ++ct)
                    acc2[rt][ct] = __builtin_amdgcn_mfma_f32_16x16x32_bf16(
                        a[rt], bb2b[kk][ct], acc2[rt][ct], 0, 0, 0);
        }
#pragma unroll
        for (int rt = 0; rt < 4; ++rt)
#pragma unroll
            for (int ct = 0; ct < 2; ++ct)
#pragma unroll
                for (int i = 0; i < 4; ++i) {
                    const int r = b0 + rt * 16 + l4 * 4 + i;
                    const int n = (w << 6) + 32 + ct * 16 + l15;
                    out[((size_t)r * S_ + s) * OUT_ + n] = acc2[rt][ct][i];
                }
    }
}

extern "C" void kernel_launch(void* const* d_in, const int* in_sizes, int n_in,
                              void* d_out, int out_size, void* d_ws, size_t ws_size,
                              hipStream_t stream) {
    const float* x  = (const float*)d_in[0];
    const float* W1 = (const float*)d_in[1];
    const float* b1 = (const float*)d_in[2];
    const float* W2 = (const float*)d_in[3];
    const float* b2 = (const float*)d_in[4];
    float* out = (float*)d_out;

    unsigned short* w1t = (unsigned short*)d_ws;                 // [S][H][IN]  bf16: 2 MiB
    unsigned short* w2t = w1t + (size_t)S_ * H_ * IN_;           // [S][OUT][H] bf16: 2 MiB

    transpose_cvt_both<<<2048, 256, 0, stream>>>(W1, W2, w1t, w2t);
    subband_fused_kernel<<<S_ * (B_ / BM_), 256, 0, stream>>>(x, w1t, b1, w2t, b2, out);
}